// Round 3
// baseline (4865.914 us; speedup 1.0000x reference)
//
#include <hip/hip_runtime.h>
#include <hip/hip_bf16.h>

#define N    4096
#define NIT  50
#define EPS  1e-8f
#define NB   256      // blocks (1 per CU)
#define NT   512      // threads per block = 8 waves
#define RPB  16       // rows per block  (N / NB)
#define CPW  512      // cols per wave   (N / 8)
#define CPL  8        // cols per lane   (CPW / 64)

// ---- bf16 helpers (bf16 = high 16 bits of f32) ----------------------------
__device__ __forceinline__ unsigned bf16_rne(float f) {
    unsigned u = __float_as_uint(f);
    return (u + 0x7FFFu + ((u >> 16) & 1u)) >> 16;
}
__device__ __forceinline__ float bf_lo(unsigned u){ return __uint_as_float(u << 16); }
__device__ __forceinline__ float bf_hi(unsigned u){ return __uint_as_float(u & 0xFFFF0000u); }

// ---- flat slot grid barrier (deterministic, no atomics-on-one-line) -------
// slots[] memset to 0 at launch; gen increases 1..2*NIT within a launch.
__device__ __forceinline__ void grid_barrier(int* slots, int b, int gen) {
    __syncthreads();
    if (threadIdx.x == 0) {
        __threadfence();   // device-scope release: flush this XCD's L2
        __hip_atomic_store(slots + b, gen, __ATOMIC_RELAXED, __HIP_MEMORY_SCOPE_AGENT);
    }
    if (threadIdx.x < 64) {
        const int l = threadIdx.x;
        bool done;
        do {
            int ok = 1;
#pragma unroll
            for (int k = 0; k < 4; ++k) {
                int v = __hip_atomic_load(slots + l + 64 * k,
                                          __ATOMIC_RELAXED, __HIP_MEMORY_SCOPE_AGENT);
                ok &= (v >= gen);
            }
            done = __all(ok);
            if (!done) __builtin_amdgcn_s_sleep(1);
        } while (!done);
    }
    __syncthreads();
    __threadfence();       // device-scope acquire: invalidate L1/L2 before reads
}

// ---------------------------------------------------------------------------
// Persistent kernel: softmax -> 50 Sinkhorn iterations -> finalize.
// Block b owns rows 16b..16b+15; wave w owns cols [512w, 512w+512);
// lane l owns 8 contiguous cols col0 = 512w + 8l. S (bf16, unnormalized
// exp(x-mx)) lives in q[16] (uint4) registers for the entire kernel.
// Row scale rn_s absorbs 1/rowsum; col scale c in global ws.
// ---------------------------------------------------------------------------
__global__ __launch_bounds__(NT, 2)
void sinkhorn_persistent(const float* __restrict__ x, float* __restrict__ out,
                         float* __restrict__ c, float* __restrict__ part,
                         int* __restrict__ slots) {
    const int b   = blockIdx.x;
    const int tid = threadIdx.x;
    const int w   = tid >> 6, l = tid & 63;
    const int row0 = b * RPB;
    const int col0 = w * CPW + l * CPL;

    __shared__ float red[8][RPB];     // cross-wave row reductions
    __shared__ float rn_s[RPB];       // running row scale (incl. 1/rowsum)
    __shared__ float mx_s[RPB];       // row maxima (for finalize)
    __shared__ float vred[32][16];    // phase-B column reduction

    const float4* xb = (const float4*)x;

    // ================= Phase 0: softmax into registers =================
    float mxl[RPB];
#pragma unroll
    for (int i = 0; i < RPB; ++i) {
        const size_t base = ((size_t)(row0 + i) * N + col0) >> 2;
        float4 a = xb[base], d = xb[base + 1];
        float m = fmaxf(fmaxf(fmaxf(a.x, a.y), fmaxf(a.z, a.w)),
                        fmaxf(fmaxf(d.x, d.y), fmaxf(d.z, d.w)));
#pragma unroll
        for (int off = 32; off; off >>= 1) m = fmaxf(m, __shfl_xor(m, off));
        if (l == 0) red[w][i] = m;
    }
    __syncthreads();
#pragma unroll
    for (int i = 0; i < RPB; ++i) {
        float m = red[0][i];
#pragma unroll
        for (int ww = 1; ww < 8; ++ww) m = fmaxf(m, red[ww][i]);
        mxl[i] = m;
    }
    if (tid == 0) {
#pragma unroll
        for (int i = 0; i < RPB; ++i) mx_s[i] = mxl[i];
    }
    __syncthreads();   // red about to be reused

    uint4 q[RPB];
#pragma unroll
    for (int i = 0; i < RPB; ++i) {
        const size_t base = ((size_t)(row0 + i) * N + col0) >> 2;
        float4 a = xb[base], d = xb[base + 1];
        float e0 = __expf(a.x - mxl[i]), e1 = __expf(a.y - mxl[i]);
        float e2 = __expf(a.z - mxl[i]), e3 = __expf(a.w - mxl[i]);
        float e4 = __expf(d.x - mxl[i]), e5 = __expf(d.y - mxl[i]);
        float e6 = __expf(d.z - mxl[i]), e7 = __expf(d.w - mxl[i]);
        uint4 pk;
        pk.x = bf16_rne(e0) | (bf16_rne(e1) << 16);
        pk.y = bf16_rne(e2) | (bf16_rne(e3) << 16);
        pk.z = bf16_rne(e4) | (bf16_rne(e5) << 16);
        pk.w = bf16_rne(e6) | (bf16_rne(e7) << 16);
        q[i] = pk;
        float s = ((e0 + e1) + (e2 + e3)) + ((e4 + e5) + (e6 + e7));
#pragma unroll
        for (int off = 32; off; off >>= 1) s += __shfl_xor(s, off);
        if (l == 0) red[w][i] = s;
    }
    __syncthreads();
    if (tid == 0) {
#pragma unroll
        for (int i = 0; i < RPB; ++i) {
            float s = red[0][i];
#pragma unroll
            for (int ww = 1; ww < 8; ++ww) s += red[ww][i];
            rn_s[i] = 1.0f / s;          // fold softmax normalization into r
        }
    }
    // rn_s read is fenced by the __syncthreads inside phase A below.

    // ================= 50 Sinkhorn iterations =================
    for (int it = 0; it < NIT; ++it) {
        // ---------- Phase A: row step + column partials ----------
        float cv[CPL];
        if (it == 0) {
#pragma unroll
            for (int e = 0; e < CPL; ++e) cv[e] = 1.0f;
        } else {
            const float4* c4 = (const float4*)(c + col0);
            float4 a = c4[0], d = c4[1];
            cv[0] = a.x; cv[1] = a.y; cv[2] = a.z; cv[3] = a.w;
            cv[4] = d.x; cv[5] = d.y; cv[6] = d.z; cv[7] = d.w;
        }

        float u_l[RPB];
#pragma unroll
        for (int i = 0; i < RPB; ++i) {
            float d0 = 0.f;
            d0 = fmaf(bf_lo(q[i].x), cv[0], d0); d0 = fmaf(bf_hi(q[i].x), cv[1], d0);
            d0 = fmaf(bf_lo(q[i].y), cv[2], d0); d0 = fmaf(bf_hi(q[i].y), cv[3], d0);
            d0 = fmaf(bf_lo(q[i].z), cv[4], d0); d0 = fmaf(bf_hi(q[i].z), cv[5], d0);
            d0 = fmaf(bf_lo(q[i].w), cv[6], d0); d0 = fmaf(bf_hi(q[i].w), cv[7], d0);
#pragma unroll
            for (int off = 32; off; off >>= 1) d0 += __shfl_xor(d0, off);
            u_l[i] = d0;
        }
        if (l == 0) {
#pragma unroll
            for (int i = 0; i < RPB; ++i) red[w][i] = u_l[i];
        }
        __syncthreads();                       // red ready (and rn_s from writer)

        float rn[RPB];
#pragma unroll
        for (int i = 0; i < RPB; ++i) {
            float u = red[0][i];
#pragma unroll
            for (int ww = 1; ww < 8; ++ww) u += red[ww][i];
            const float ro = rn_s[i];
            rn[i] = ro / fmaf(ro, u, EPS);
        }
        __syncthreads();                       // all rn_s reads complete
        if (tid == 0) {
#pragma unroll
            for (int i = 0; i < RPB; ++i) rn_s[i] = rn[i];
        }

        float acc[CPL];
#pragma unroll
        for (int e = 0; e < CPL; ++e) acc[e] = 0.f;
#pragma unroll
        for (int i = 0; i < RPB; ++i) {
            acc[0] = fmaf(rn[i], bf_lo(q[i].x), acc[0]);
            acc[1] = fmaf(rn[i], bf_hi(q[i].x), acc[1]);
            acc[2] = fmaf(rn[i], bf_lo(q[i].y), acc[2]);
            acc[3] = fmaf(rn[i], bf_hi(q[i].y), acc[3]);
            acc[4] = fmaf(rn[i], bf_lo(q[i].z), acc[4]);
            acc[5] = fmaf(rn[i], bf_hi(q[i].z), acc[5]);
            acc[6] = fmaf(rn[i], bf_lo(q[i].w), acc[6]);
            acc[7] = fmaf(rn[i], bf_hi(q[i].w), acc[7]);
        }
        float4* p4 = (float4*)(part + (size_t)b * N + col0);
        p4[0] = make_float4(acc[0], acc[1], acc[2], acc[3]);
        p4[1] = make_float4(acc[4], acc[5], acc[6], acc[7]);

        grid_barrier(slots, b, 2 * it + 1);

        // ---------- Phase B: columns 16b..16b+15 ----------
        {
            const int jc = tid & 15, cs = tid >> 4;     // cs = 0..31
            const int j = b * 16 + jc;
            float v = 0.f;
#pragma unroll
            for (int s = 0; s < 8; ++s)
                v += part[(size_t)(cs + 32 * s) * N + j];
            vred[cs][jc] = v;
        }
        __syncthreads();
        if (tid < 16) {
            const int j = b * 16 + tid;
            float v = 0.f;
#pragma unroll
            for (int cs = 0; cs < 32; ++cs) v += vred[cs][tid];
            const float cc = it ? c[j] : 1.0f;
            c[j] = cc / fmaf(cc, v, EPS);
        }
        grid_barrier(slots, b, 2 * it + 2);
    }

    // ================= Finalize: out = rn * exp(x - mx) * c =================
    float cfin[CPL];
    {
        const float4* c4 = (const float4*)(c + col0);
        float4 a = c4[0], d = c4[1];
        cfin[0] = a.x; cfin[1] = a.y; cfin[2] = a.z; cfin[3] = a.w;
        cfin[4] = d.x; cfin[5] = d.y; cfin[6] = d.z; cfin[7] = d.w;
    }
    float4* ob = (float4*)out;
#pragma unroll
    for (int i = 0; i < RPB; ++i) {
        const size_t base = ((size_t)(row0 + i) * N + col0) >> 2;
        float4 a = xb[base], d = xb[base + 1];
        const float s = rn_s[i];
        const float m = mx_s[i];
        float4 o0, o1;
        o0.x = s * __expf(a.x - m) * cfin[0];
        o0.y = s * __expf(a.y - m) * cfin[1];
        o0.z = s * __expf(a.z - m) * cfin[2];
        o0.w = s * __expf(a.w - m) * cfin[3];
        o1.x = s * __expf(d.x - m) * cfin[4];
        o1.y = s * __expf(d.y - m) * cfin[5];
        o1.z = s * __expf(d.z - m) * cfin[6];
        o1.w = s * __expf(d.w - m) * cfin[7];
        ob[base]     = o0;
        ob[base + 1] = o1;
    }
}

extern "C" void kernel_launch(void* const* d_in, const int* in_sizes, int n_in,
                              void* d_out, int out_size, void* d_ws, size_t ws_size,
                              hipStream_t stream) {
    const float* logits = (const float*)d_in[0];
    float* out = (float*)d_out;
    float* ws  = (float*)d_ws;

    float* c    = ws;                                   // [N]
    float* part = ws + N;                               // [NB][N] = 4 MB
    int*   slots = (int*)(ws + N + (size_t)NB * N);     // [NB]

    hipMemsetAsync(slots, 0, NB * sizeof(int), stream); // barrier gen starts at 1

    void* args[] = { (void*)&logits, (void*)&out, (void*)&c, (void*)&part, (void*)&slots };
    hipError_t e = hipLaunchCooperativeKernel((const void*)sinkhorn_persistent,
                                              dim3(NB), dim3(NT), args, 0, stream);
    if (e != hipSuccess) {
        // Fallback: 256 blocks at 1 block/CU fit co-resident on 256 CUs.
        sinkhorn_persistent<<<dim3(NB), dim3(NT), 0, stream>>>(logits, out, c, part, slots);
    }
}

// Round 4
// 1138.182 us; speedup vs baseline: 4.2752x; 4.2752x over previous
//
#include <hip/hip_runtime.h>
#include <hip/hip_bf16.h>

#define N            4096
#define NIT          50
#define EPS          1e-8f
#define PASS_BLOCKS  256
#define ROWS_PER_BLOCK (N / PASS_BLOCKS)     // 16
#define ROWS_PER_WAVE  (ROWS_PER_BLOCK / 4)  // 4

// ---- bf16 helpers (bf16 = high 16 bits of f32) ----------------------------
__device__ __forceinline__ unsigned bf16_rne(float f) {
    unsigned u = __float_as_uint(f);
    return (u + 0x7FFFu + ((u >> 16) & 1u)) >> 16;
}
__device__ __forceinline__ float bf_lo(unsigned u){ return __uint_as_float(u << 16); }
__device__ __forceinline__ float bf_hi(unsigned u){ return __uint_as_float(u & 0xFFFF0000u); }

// ---------------------------------------------------------------------------
// Kernel 1: row softmax of logits -> Sb (bf16), store per-row max & 1/sum,
//           init r = c = 1.  (No f32 S is materialized.)
// ---------------------------------------------------------------------------
__global__ void softmax_rows(const float* __restrict__ x, unsigned* __restrict__ Sb_u32,
                             float* __restrict__ mxv, float* __restrict__ siv,
                             float* __restrict__ r, float* __restrict__ c) {
    const int row = blockIdx.x;
    const int tid = threadIdx.x;
    const float4* xr = (const float4*)(x + (size_t)row * N);

    float4 v[4];
    float mx = -3.0e38f;
#pragma unroll
    for (int t = 0; t < 4; ++t) {
        v[t] = xr[tid + 256 * t];
        mx = fmaxf(mx, fmaxf(fmaxf(v[t].x, v[t].y), fmaxf(v[t].z, v[t].w)));
    }

    __shared__ float sm[4];
#pragma unroll
    for (int off = 32; off; off >>= 1) mx = fmaxf(mx, __shfl_down(mx, off));
    const int wid = tid >> 6, lane = tid & 63;
    if (lane == 0) sm[wid] = mx;
    __syncthreads();
    mx = fmaxf(fmaxf(sm[0], sm[1]), fmaxf(sm[2], sm[3]));
    __syncthreads();

    float sum = 0.f;
#pragma unroll
    for (int t = 0; t < 4; ++t) {
        v[t].x = __expf(v[t].x - mx);
        v[t].y = __expf(v[t].y - mx);
        v[t].z = __expf(v[t].z - mx);
        v[t].w = __expf(v[t].w - mx);
        sum += (v[t].x + v[t].y) + (v[t].z + v[t].w);
    }
#pragma unroll
    for (int off = 32; off; off >>= 1) sum += __shfl_down(sum, off);
    if (lane == 0) sm[wid] = sum;
    __syncthreads();
    sum = (sm[0] + sm[1]) + (sm[2] + sm[3]);

    const float inv = 1.0f / sum;
    uint2* Sb2 = (uint2*)(Sb_u32) + (size_t)row * (N / 4);   // uint2 = 4 bf16
#pragma unroll
    for (int t = 0; t < 4; ++t) {
        const int f = tid + 256 * t;
        uint2 pk;
        pk.x = bf16_rne(v[t].x * inv) | (bf16_rne(v[t].y * inv) << 16);
        pk.y = bf16_rne(v[t].z * inv) | (bf16_rne(v[t].w * inv) << 16);
        Sb2[f] = pk;
    }
    if (tid == 0) { mxv[row] = mx; siv[row] = inv; }

    if (blockIdx.x < 16) {
        const int k = blockIdx.x * 256 + tid;
        r[k] = 1.0f;
        c[k] = 1.0f;
    }
}

// ---------------------------------------------------------------------------
// Kernel 2 (fused row+col step): per block = 16 rows (4 per wave).
//  - cache c in regs; load row (bf16) into regs; u = dot(row, c) via wave
//    butterfly; r_new = r/(r*u+eps); acc[col] += r_new * row  (no re-read).
//  - LDS-reduce 4 waves -> part[block][col].
// ---------------------------------------------------------------------------
__global__ __launch_bounds__(256, 2)
void sinkhorn_pass(const uint4* __restrict__ Sb, float* __restrict__ r,
                   const float* __restrict__ c, float* __restrict__ part) {
    __shared__ float lds[4 * N];   // 64 KB
    const int b = blockIdx.x, tid = threadIdx.x;
    const int w = tid >> 6, l = tid & 63;

    // cache c: lane covers cols (l+64k)*8 + e, k=0..7, e=0..7
    float cv[64];
    const float4* c4 = (const float4*)c;
#pragma unroll
    for (int k = 0; k < 8; ++k) {
        const int f4 = (l + 64 * k) * 2;
        float4 a = c4[f4], d = c4[f4 + 1];
        cv[k*8+0]=a.x; cv[k*8+1]=a.y; cv[k*8+2]=a.z; cv[k*8+3]=a.w;
        cv[k*8+4]=d.x; cv[k*8+5]=d.y; cv[k*8+6]=d.z; cv[k*8+7]=d.w;
    }
    float acc[64];
#pragma unroll
    for (int e = 0; e < 64; ++e) acc[e] = 0.f;

    const int i0 = b * ROWS_PER_BLOCK + w * ROWS_PER_WAVE;
#pragma unroll
    for (int rr_ = 0; rr_ < ROWS_PER_WAVE; ++rr_) {
        const int i = i0 + rr_;
        const uint4* row = Sb + (size_t)i * (N / 8);
        uint4 q[8];
#pragma unroll
        for (int k = 0; k < 8; ++k) q[k] = row[l + 64 * k];

        float dot = 0.f;
#pragma unroll
        for (int k = 0; k < 8; ++k) {
            dot = fmaf(bf_lo(q[k].x), cv[k*8+0], dot);
            dot = fmaf(bf_hi(q[k].x), cv[k*8+1], dot);
            dot = fmaf(bf_lo(q[k].y), cv[k*8+2], dot);
            dot = fmaf(bf_hi(q[k].y), cv[k*8+3], dot);
            dot = fmaf(bf_lo(q[k].z), cv[k*8+4], dot);
            dot = fmaf(bf_hi(q[k].z), cv[k*8+5], dot);
            dot = fmaf(bf_lo(q[k].w), cv[k*8+6], dot);
            dot = fmaf(bf_hi(q[k].w), cv[k*8+7], dot);
        }
#pragma unroll
        for (int off = 32; off; off >>= 1) dot += __shfl_xor(dot, off);

        const float ro = r[i];
        const float rn = ro / fmaf(ro, dot, EPS);
        if (l == 0) r[i] = rn;

#pragma unroll
        for (int k = 0; k < 8; ++k) {
            acc[k*8+0] = fmaf(rn, bf_lo(q[k].x), acc[k*8+0]);
            acc[k*8+1] = fmaf(rn, bf_hi(q[k].x), acc[k*8+1]);
            acc[k*8+2] = fmaf(rn, bf_lo(q[k].y), acc[k*8+2]);
            acc[k*8+3] = fmaf(rn, bf_hi(q[k].y), acc[k*8+3]);
            acc[k*8+4] = fmaf(rn, bf_lo(q[k].z), acc[k*8+4]);
            acc[k*8+5] = fmaf(rn, bf_hi(q[k].z), acc[k*8+5]);
            acc[k*8+6] = fmaf(rn, bf_lo(q[k].w), acc[k*8+6]);
            acc[k*8+7] = fmaf(rn, bf_hi(q[k].w), acc[k*8+7]);
        }
    }

    // wave partials -> LDS in a permuted, conflict-free layout:
    // lds4[w*1024 + (2k+h)*64 + l]  holds column-float4  2l + 128k + h
    float4* lw = (float4*)lds + w * 1024;
#pragma unroll
    for (int k = 0; k < 8; ++k) {
#pragma unroll
        for (int h = 0; h < 2; ++h) {
            float4 t4;
            t4.x = acc[k*8 + 4*h + 0];
            t4.y = acc[k*8 + 4*h + 1];
            t4.z = acc[k*8 + 4*h + 2];
            t4.w = acc[k*8 + 4*h + 3];
            lw[(2*k + h) * 64 + l] = t4;
        }
    }
    __syncthreads();

    const float4* lr = (const float4*)lds;
    float4* p4 = (float4*)(part + (size_t)b * N);
#pragma unroll
    for (int m = 0; m < 4; ++m) {
        const int p = tid + 256 * m;
        const int j = p >> 6, ll = p & 63;
        float4 s0 = lr[p], s1 = lr[1024 + p], s2 = lr[2048 + p], s3 = lr[3072 + p];
        float4 s;
        s.x = (s0.x + s1.x) + (s2.x + s3.x);
        s.y = (s0.y + s1.y) + (s2.y + s3.y);
        s.z = (s0.z + s1.z) + (s2.z + s3.z);
        s.w = (s0.w + s1.w) + (s2.w + s3.w);
        const int col4 = 2 * ll + 128 * (j >> 1) + (j & 1);
        p4[col4] = s;
    }
}

// ---------------------------------------------------------------------------
// Kernel 3: v[j] = sum_b part[b][j];  c[j] = c[j]/(c[j]*v+eps)
// 128 blocks x 256 threads; block owns 32 columns; 8-way chunk split + LDS.
// ---------------------------------------------------------------------------
__global__ void col_update(const float* __restrict__ part, float* __restrict__ c) {
    __shared__ float red[8][32];
    const int j0 = blockIdx.x * 32;
    const int jc = threadIdx.x & 31;
    const int g  = threadIdx.x >> 5;           // 0..7
    const int j  = j0 + jc;
    float v = 0.f;
#pragma unroll
    for (int k = 0; k < PASS_BLOCKS / 8; ++k)
        v += part[(size_t)(g * (PASS_BLOCKS / 8) + k) * N + j];
    red[g][jc] = v;
    __syncthreads();
    if (threadIdx.x < 32) {
        float s = 0.f;
#pragma unroll
        for (int g2 = 0; g2 < 8; ++g2) s += red[g2][threadIdx.x];
        const float cc = c[j0 + threadIdx.x];
        c[j0 + threadIdx.x] = cc / fmaf(cc, s, EPS);
    }
}

// ---------------------------------------------------------------------------
// Kernel 4: out[i][j] = r[i] * (exp(x[i][j]-mx[i])*siv[i]) * c[j]
// ---------------------------------------------------------------------------
__global__ void finalize(const float* __restrict__ x, const float* __restrict__ r,
                         const float* __restrict__ c, const float* __restrict__ mxv,
                         const float* __restrict__ siv, float* __restrict__ out) {
    const int row = blockIdx.x;
    const int tid = threadIdx.x;
    const float mx = mxv[row];
    const float sr = r[row] * siv[row];
    const float4* xr = (const float4*)(x + (size_t)row * N);
    float4* o4 = (float4*)(out + (size_t)row * N);
    const float4* c4 = (const float4*)c;
#pragma unroll
    for (int t = 0; t < 4; ++t) {
        const int k = tid + 256 * t;
        float4 xv = xr[k], cc = c4[k];
        float4 o;
        o.x = sr * __expf(xv.x - mx) * cc.x;
        o.y = sr * __expf(xv.y - mx) * cc.y;
        o.z = sr * __expf(xv.z - mx) * cc.z;
        o.w = sr * __expf(xv.w - mx) * cc.w;
        o4[k] = o;
    }
}

extern "C" void kernel_launch(void* const* d_in, const int* in_sizes, int n_in,
                              void* d_out, int out_size, void* d_ws, size_t ws_size,
                              hipStream_t stream) {
    const float* logits = (const float*)d_in[0];
    float* out = (float*)d_out;
    float* ws = (float*)d_ws;

    float* r    = ws;                          // [N]
    float* c    = ws + N;                      // [N]
    float* mxv  = ws + 2 * N;                  // [N]
    float* siv  = ws + 3 * N;                  // [N]
    float* part = ws + 4 * N;                  // [PASS_BLOCKS][N] = 4 MB
    unsigned* Sb = (unsigned*)(part + (size_t)PASS_BLOCKS * N);  // bf16 [N][N] = 32 MB

    softmax_rows<<<N, 256, 0, stream>>>(logits, Sb, mxv, siv, r, c);

    for (int it = 0; it < NIT; ++it) {
        sinkhorn_pass<<<PASS_BLOCKS, 256, 0, stream>>>((const uint4*)Sb, r, c, part);
        col_update  <<<128,          256, 0, stream>>>(part, c);
    }

    finalize<<<N, 256, 0, stream>>>(logits, r, c, mxv, siv, out);
}

// Round 5
// 671.539 us; speedup vs baseline: 7.2459x; 1.6949x over previous
//
#include <hip/hip_runtime.h>
#include <hip/hip_bf16.h>

#define N            4096
#define NIT          50
#define EPS          1e-8f
#define PASS_BLOCKS  256
#define ROWS_PER_BLOCK 16            // rows per block; 8 waves -> 2 rows/wave

// ---- bf16 helpers (bf16 = high 16 bits of f32) ----------------------------
__device__ __forceinline__ unsigned bf16_rne(float f) {
    unsigned u = __float_as_uint(f);
    return (u + 0x7FFFu + ((u >> 16) & 1u)) >> 16;
}
__device__ __forceinline__ float bf_lo(unsigned u){ return __uint_as_float(u << 16); }
__device__ __forceinline__ float bf_hi(unsigned u){ return __uint_as_float(u & 0xFFFF0000u); }

// ---------------------------------------------------------------------------
// Kernel 1: row softmax of logits -> Sb (bf16), store per-row max & 1/sum,
//           init r = c = 1.
// ---------------------------------------------------------------------------
__global__ void softmax_rows(const float* __restrict__ x, unsigned* __restrict__ Sb_u32,
                             float* __restrict__ mxv, float* __restrict__ siv,
                             float* __restrict__ r, float* __restrict__ c) {
    const int row = blockIdx.x;
    const int tid = threadIdx.x;
    const float4* xr = (const float4*)(x + (size_t)row * N);

    float4 v[4];
    float mx = -3.0e38f;
#pragma unroll
    for (int t = 0; t < 4; ++t) {
        v[t] = xr[tid + 256 * t];
        mx = fmaxf(mx, fmaxf(fmaxf(v[t].x, v[t].y), fmaxf(v[t].z, v[t].w)));
    }

    __shared__ float sm[4];
#pragma unroll
    for (int off = 32; off; off >>= 1) mx = fmaxf(mx, __shfl_down(mx, off));
    const int wid = tid >> 6, lane = tid & 63;
    if (lane == 0) sm[wid] = mx;
    __syncthreads();
    mx = fmaxf(fmaxf(sm[0], sm[1]), fmaxf(sm[2], sm[3]));
    __syncthreads();

    float sum = 0.f;
#pragma unroll
    for (int t = 0; t < 4; ++t) {
        v[t].x = __expf(v[t].x - mx);
        v[t].y = __expf(v[t].y - mx);
        v[t].z = __expf(v[t].z - mx);
        v[t].w = __expf(v[t].w - mx);
        sum += (v[t].x + v[t].y) + (v[t].z + v[t].w);
    }
#pragma unroll
    for (int off = 32; off; off >>= 1) sum += __shfl_down(sum, off);
    if (lane == 0) sm[wid] = sum;
    __syncthreads();
    sum = (sm[0] + sm[1]) + (sm[2] + sm[3]);

    const float inv = 1.0f / sum;
    uint2* Sb2 = (uint2*)(Sb_u32) + (size_t)row * (N / 4);
#pragma unroll
    for (int t = 0; t < 4; ++t) {
        const int f = tid + 256 * t;
        uint2 pk;
        pk.x = bf16_rne(v[t].x * inv) | (bf16_rne(v[t].y * inv) << 16);
        pk.y = bf16_rne(v[t].z * inv) | (bf16_rne(v[t].w * inv) << 16);
        Sb2[f] = pk;
    }
    if (tid == 0) { mxv[row] = mx; siv[row] = inv; }

    if (blockIdx.x < 16) {
        const int k = blockIdx.x * 256 + tid;
        r[k] = 1.0f;
        c[k] = 1.0f;
    }
}

// ---------------------------------------------------------------------------
// Kernel 2 (fused row+col step): 256 blocks x 512 threads (8 waves).
// Block owns 16 rows, wave owns 2 rows spanning all 4096 cols; lane l holds
// cols (l+64k)*8..+7.  Both rows' loads issued up-front (16 in flight).
// Cross-wave col-partial reduce: two-stage in 64 KB LDS, then coalesced
// part write.
// ---------------------------------------------------------------------------
__global__ __launch_bounds__(512, 2)
void sinkhorn_pass(const uint4* __restrict__ Sb, float* __restrict__ r,
                   const float* __restrict__ c, float* __restrict__ part) {
    __shared__ float lds[4 * N];   // 64 KB: 4 col-partial buffers of 4096 f32
    const int b = blockIdx.x, tid = threadIdx.x;
    const int w = tid >> 6, l = tid & 63;

    // cache c in regs
    float cv[64];
    const float4* c4 = (const float4*)c;
#pragma unroll
    for (int k = 0; k < 8; ++k) {
        const int f4 = (l + 64 * k) * 2;
        float4 a = c4[f4], d = c4[f4 + 1];
        cv[k*8+0]=a.x; cv[k*8+1]=a.y; cv[k*8+2]=a.z; cv[k*8+3]=a.w;
        cv[k*8+4]=d.x; cv[k*8+5]=d.y; cv[k*8+6]=d.z; cv[k*8+7]=d.w;
    }

    const int i0 = b * ROWS_PER_BLOCK + w * 2;
    const uint4* r0p = Sb + (size_t)i0 * (N / 8);
    const uint4* r1p = r0p + (N / 8);
    uint4 q0[8], q1[8];
#pragma unroll
    for (int k = 0; k < 8; ++k) q0[k] = r0p[l + 64 * k];
#pragma unroll
    for (int k = 0; k < 8; ++k) q1[k] = r1p[l + 64 * k];
    const float ro0 = r[i0], ro1 = r[i0 + 1];

    float d0 = 0.f, d1 = 0.f;
#pragma unroll
    for (int k = 0; k < 8; ++k) {
        d0 = fmaf(bf_lo(q0[k].x), cv[k*8+0], d0);
        d0 = fmaf(bf_hi(q0[k].x), cv[k*8+1], d0);
        d0 = fmaf(bf_lo(q0[k].y), cv[k*8+2], d0);
        d0 = fmaf(bf_hi(q0[k].y), cv[k*8+3], d0);
        d0 = fmaf(bf_lo(q0[k].z), cv[k*8+4], d0);
        d0 = fmaf(bf_hi(q0[k].z), cv[k*8+5], d0);
        d0 = fmaf(bf_lo(q0[k].w), cv[k*8+6], d0);
        d0 = fmaf(bf_hi(q0[k].w), cv[k*8+7], d0);
        d1 = fmaf(bf_lo(q1[k].x), cv[k*8+0], d1);
        d1 = fmaf(bf_hi(q1[k].x), cv[k*8+1], d1);
        d1 = fmaf(bf_lo(q1[k].y), cv[k*8+2], d1);
        d1 = fmaf(bf_hi(q1[k].y), cv[k*8+3], d1);
        d1 = fmaf(bf_lo(q1[k].z), cv[k*8+4], d1);
        d1 = fmaf(bf_hi(q1[k].z), cv[k*8+5], d1);
        d1 = fmaf(bf_lo(q1[k].w), cv[k*8+6], d1);
        d1 = fmaf(bf_hi(q1[k].w), cv[k*8+7], d1);
    }
#pragma unroll
    for (int off = 32; off; off >>= 1) {
        d0 += __shfl_xor(d0, off);
        d1 += __shfl_xor(d1, off);
    }

    const float rn0 = ro0 / fmaf(ro0, d0, EPS);
    const float rn1 = ro1 / fmaf(ro1, d1, EPS);
    if (l == 0) { r[i0] = rn0; r[i0 + 1] = rn1; }

    // acc = rn0*row0 + rn1*row1
    float acc[64];
#pragma unroll
    for (int k = 0; k < 8; ++k) {
        acc[k*8+0] = fmaf(rn0, bf_lo(q0[k].x), rn1 * bf_lo(q1[k].x));
        acc[k*8+1] = fmaf(rn0, bf_hi(q0[k].x), rn1 * bf_hi(q1[k].x));
        acc[k*8+2] = fmaf(rn0, bf_lo(q0[k].y), rn1 * bf_lo(q1[k].y));
        acc[k*8+3] = fmaf(rn0, bf_hi(q0[k].y), rn1 * bf_hi(q1[k].y));
        acc[k*8+4] = fmaf(rn0, bf_lo(q0[k].z), rn1 * bf_lo(q1[k].z));
        acc[k*8+5] = fmaf(rn0, bf_hi(q0[k].z), rn1 * bf_hi(q1[k].z));
        acc[k*8+6] = fmaf(rn0, bf_lo(q0[k].w), rn1 * bf_lo(q1[k].w));
        acc[k*8+7] = fmaf(rn0, bf_hi(q0[k].w), rn1 * bf_hi(q1[k].w));
    }

    // two-stage cross-wave reduce in LDS.
    // buffer layout: lds4[(w&3)*1024 + (2k+h)*64 + l] holds column-float4 2l+128k+h
    float4* lw = (float4*)lds + (w & 3) * 1024;
    if (w < 4) {
#pragma unroll
        for (int k = 0; k < 8; ++k) {
#pragma unroll
            for (int h = 0; h < 2; ++h) {
                lw[(2*k + h) * 64 + l] = make_float4(acc[k*8+4*h+0], acc[k*8+4*h+1],
                                                     acc[k*8+4*h+2], acc[k*8+4*h+3]);
            }
        }
    }
    __syncthreads();
    if (w >= 4) {
#pragma unroll
        for (int k = 0; k < 8; ++k) {
#pragma unroll
            for (int h = 0; h < 2; ++h) {
                const int idx = (2*k + h) * 64 + l;
                float4 t = lw[idx];
                t.x += acc[k*8+4*h+0];
                t.y += acc[k*8+4*h+1];
                t.z += acc[k*8+4*h+2];
                t.w += acc[k*8+4*h+3];
                lw[idx] = t;
            }
        }
    }
    __syncthreads();

    // final: sum the 4 buffers at the permuted index, write part contiguously
    const float4* lr = (const float4*)lds;
    float4* p4 = (float4*)(part + (size_t)b * N);
#pragma unroll
    for (int m = 0; m < 2; ++m) {
        const int j4  = tid + 512 * m;                                   // output float4 idx
        const int idx = ((2 * (j4 >> 7) + (j4 & 1)) << 6) + ((j4 >> 1) & 63);
        float4 s0 = lr[idx], s1 = lr[1024 + idx], s2 = lr[2048 + idx], s3 = lr[3072 + idx];
        float4 s;
        s.x = (s0.x + s1.x) + (s2.x + s3.x);
        s.y = (s0.y + s1.y) + (s2.y + s3.y);
        s.z = (s0.z + s1.z) + (s2.z + s3.z);
        s.w = (s0.w + s1.w) + (s2.w + s3.w);
        p4[j4] = s;
    }
}

// ---------------------------------------------------------------------------
// Kernel 3: v[j] = sum_b part[b][j];  c[j] = c[j]/(c[j]*v+eps)
// 64 blocks x 256 threads; block owns 64 consecutive cols (256 B coalesced
// wave reads); 4-way chunk split + LDS reduce.
// ---------------------------------------------------------------------------
__global__ void col_update(const float* __restrict__ part, float* __restrict__ c) {
    __shared__ float red[4][64];
    const int j0 = blockIdx.x * 64;
    const int jc = threadIdx.x & 63;
    const int g  = threadIdx.x >> 6;           // 0..3
    const int j  = j0 + jc;
    float v = 0.f;
#pragma unroll 8
    for (int k = 0; k < PASS_BLOCKS / 4; ++k)
        v += part[(size_t)(g * (PASS_BLOCKS / 4) + k) * N + j];
    red[g][jc] = v;
    __syncthreads();
    if (threadIdx.x < 64) {
        const float s = (red[0][jc] + red[1][jc]) + (red[2][jc] + red[3][jc]);
        const float cc = c[j];
        c[j] = cc / fmaf(cc, s, EPS);
    }
}

// ---------------------------------------------------------------------------
// Kernel 4: out[i][j] = r[i] * (exp(x[i][j]-mx[i])*siv[i]) * c[j]
// ---------------------------------------------------------------------------
__global__ void finalize(const float* __restrict__ x, const float* __restrict__ r,
                         const float* __restrict__ c, const float* __restrict__ mxv,
                         const float* __restrict__ siv, float* __restrict__ out) {
    const int row = blockIdx.x;
    const int tid = threadIdx.x;
    const float mx = mxv[row];
    const float sr = r[row] * siv[row];
    const float4* xr = (const float4*)(x + (size_t)row * N);
    float4* o4 = (float4*)(out + (size_t)row * N);
    const float4* c4 = (const float4*)c;
#pragma unroll
    for (int t = 0; t < 4; ++t) {
        const int k = tid + 256 * t;
        float4 xv = xr[k], cc = c4[k];
        float4 o;
        o.x = sr * __expf(xv.x - mx) * cc.x;
        o.y = sr * __expf(xv.y - mx) * cc.y;
        o.z = sr * __expf(xv.z - mx) * cc.z;
        o.w = sr * __expf(xv.w - mx) * cc.w;
        o4[k] = o;
    }
}

extern "C" void kernel_launch(void* const* d_in, const int* in_sizes, int n_in,
                              void* d_out, int out_size, void* d_ws, size_t ws_size,
                              hipStream_t stream) {
    const float* logits = (const float*)d_in[0];
    float* out = (float*)d_out;
    float* ws = (float*)d_ws;

    float* r    = ws;                          // [N]
    float* c    = ws + N;                      // [N]
    float* mxv  = ws + 2 * N;                  // [N]
    float* siv  = ws + 3 * N;                  // [N]
    float* part = ws + 4 * N;                  // [PASS_BLOCKS][N] = 4 MB
    unsigned* Sb = (unsigned*)(part + (size_t)PASS_BLOCKS * N);  // bf16 [N][N] = 32 MB

    softmax_rows<<<N, 256, 0, stream>>>(logits, Sb, mxv, siv, r, c);

    for (int it = 0; it < NIT; ++it) {
        sinkhorn_pass<<<PASS_BLOCKS, 512, 0, stream>>>((const uint4*)Sb, r, c, part);
        col_update  <<<64,           256, 0, stream>>>(part, c);
    }

    finalize<<<N, 256, 0, stream>>>(logits, r, c, mxv, siv, out);
}

// Round 6
// 645.588 us; speedup vs baseline: 7.5372x; 1.0402x over previous
//
#include <hip/hip_runtime.h>
#include <hip/hip_bf16.h>

#define N            4096
#define NIT          50
#define EPS          1e-8f
#define PASS_BLOCKS  256

// ---- bf16 helpers (bf16 = high 16 bits of f32) ----------------------------
__device__ __forceinline__ unsigned bf16_rne(float f) {
    unsigned u = __float_as_uint(f);
    return (u + 0x7FFFu + ((u >> 16) & 1u)) >> 16;
}
__device__ __forceinline__ float bf_lo(unsigned u){ return __uint_as_float(u << 16); }
__device__ __forceinline__ float bf_hi(unsigned u){ return __uint_as_float(u & 0xFFFF0000u); }

// ---------------------------------------------------------------------------
// Kernel 1: row softmax of logits -> Sb (bf16 normalized softmax),
//           init r = c = 1.
// ---------------------------------------------------------------------------
__global__ void softmax_rows(const float* __restrict__ x, unsigned* __restrict__ Sb_u32,
                             float* __restrict__ r, float* __restrict__ c) {
    const int row = blockIdx.x;
    const int tid = threadIdx.x;
    const float4* xr = (const float4*)(x + (size_t)row * N);

    float4 v[4];
    float mx = -3.0e38f;
#pragma unroll
    for (int t = 0; t < 4; ++t) {
        v[t] = xr[tid + 256 * t];
        mx = fmaxf(mx, fmaxf(fmaxf(v[t].x, v[t].y), fmaxf(v[t].z, v[t].w)));
    }

    __shared__ float sm[4];
#pragma unroll
    for (int off = 32; off; off >>= 1) mx = fmaxf(mx, __shfl_down(mx, off));
    const int wid = tid >> 6, lane = tid & 63;
    if (lane == 0) sm[wid] = mx;
    __syncthreads();
    mx = fmaxf(fmaxf(sm[0], sm[1]), fmaxf(sm[2], sm[3]));
    __syncthreads();

    float sum = 0.f;
#pragma unroll
    for (int t = 0; t < 4; ++t) {
        v[t].x = __expf(v[t].x - mx);
        v[t].y = __expf(v[t].y - mx);
        v[t].z = __expf(v[t].z - mx);
        v[t].w = __expf(v[t].w - mx);
        sum += (v[t].x + v[t].y) + (v[t].z + v[t].w);
    }
#pragma unroll
    for (int off = 32; off; off >>= 1) sum += __shfl_down(sum, off);
    if (lane == 0) sm[wid] = sum;
    __syncthreads();
    sum = (sm[0] + sm[1]) + (sm[2] + sm[3]);

    const float inv = 1.0f / sum;
    uint2* Sb2 = (uint2*)(Sb_u32) + (size_t)row * (N / 4);
#pragma unroll
    for (int t = 0; t < 4; ++t) {
        const int f = tid + 256 * t;
        uint2 pk;
        pk.x = bf16_rne(v[t].x * inv) | (bf16_rne(v[t].y * inv) << 16);
        pk.y = bf16_rne(v[t].z * inv) | (bf16_rne(v[t].w * inv) << 16);
        Sb2[f] = pk;
    }

    if (blockIdx.x < 16) {
        const int k = blockIdx.x * 256 + tid;
        r[k] = 1.0f;
        c[k] = 1.0f;
    }
}

// ---------------------------------------------------------------------------
// Kernel 2 (fused row+col step): 256 blocks x 1024 threads (16 waves).
// Block owns 16 rows. Wave w = (rowpair p = w>>1, col-half h = w&1):
// rows {2p, 2p+1}, cols [2048h, 2048h+2048). Lane holds 32 cols/row.
// Registers: q 2x16, cv 32, acc 32 -> ~115 VGPR => 4 waves/SIMD.
// Per-row dot is reduced across the two half-waves via small LDS array.
// Column partials: 8 buffers (4 per half) x 2048 f32, permuted conflict-free
// layout, then coalesced part write.
// ---------------------------------------------------------------------------
__global__ __launch_bounds__(1024, 4)
void sinkhorn_pass(const uint4* __restrict__ Sb, float* __restrict__ r,
                   const float* __restrict__ c, float* __restrict__ part) {
    __shared__ float lds[8 * 2048];       // 64 KB: 8 col-partial buffers
    __shared__ float red_u[8][2][2];      // [rowpair][half][row]
    const int b = blockIdx.x, tid = threadIdx.x;
    const int w = tid >> 6, l = tid & 63;
    const int p = w >> 1, h = w & 1;

    // cache this half's c slice: 32 floats
    float cv[32];
    const float4* c4 = (const float4*)c;
#pragma unroll
    for (int k = 0; k < 4; ++k) {
        const int f4 = h * 512 + (l + 64 * k) * 2;
        float4 a = c4[f4], d = c4[f4 + 1];
        cv[k*8+0]=a.x; cv[k*8+1]=a.y; cv[k*8+2]=a.z; cv[k*8+3]=a.w;
        cv[k*8+4]=d.x; cv[k*8+5]=d.y; cv[k*8+6]=d.z; cv[k*8+7]=d.w;
    }

    const int i0 = b * 16 + 2 * p;
    const uint4* r0p = Sb + (size_t)i0 * (N / 8) + h * 256;
    const uint4* r1p = r0p + (N / 8);
    uint4 q0[4], q1[4];
#pragma unroll
    for (int k = 0; k < 4; ++k) q0[k] = r0p[l + 64 * k];
#pragma unroll
    for (int k = 0; k < 4; ++k) q1[k] = r1p[l + 64 * k];
    const float ro0 = r[i0], ro1 = r[i0 + 1];

    // half-dot, 2 independent chains per row
    float d0a = 0.f, d0b = 0.f, d1a = 0.f, d1b = 0.f;
#pragma unroll
    for (int k = 0; k < 4; ++k) {
        d0a = fmaf(bf_lo(q0[k].x), cv[k*8+0], d0a);
        d0b = fmaf(bf_hi(q0[k].x), cv[k*8+1], d0b);
        d0a = fmaf(bf_lo(q0[k].y), cv[k*8+2], d0a);
        d0b = fmaf(bf_hi(q0[k].y), cv[k*8+3], d0b);
        d0a = fmaf(bf_lo(q0[k].z), cv[k*8+4], d0a);
        d0b = fmaf(bf_hi(q0[k].z), cv[k*8+5], d0b);
        d0a = fmaf(bf_lo(q0[k].w), cv[k*8+6], d0a);
        d0b = fmaf(bf_hi(q0[k].w), cv[k*8+7], d0b);
        d1a = fmaf(bf_lo(q1[k].x), cv[k*8+0], d1a);
        d1b = fmaf(bf_hi(q1[k].x), cv[k*8+1], d1b);
        d1a = fmaf(bf_lo(q1[k].y), cv[k*8+2], d1a);
        d1b = fmaf(bf_hi(q1[k].y), cv[k*8+3], d1b);
        d1a = fmaf(bf_lo(q1[k].z), cv[k*8+4], d1a);
        d1b = fmaf(bf_hi(q1[k].z), cv[k*8+5], d1b);
        d1a = fmaf(bf_lo(q1[k].w), cv[k*8+6], d1a);
        d1b = fmaf(bf_hi(q1[k].w), cv[k*8+7], d1b);
    }
    float d0 = d0a + d0b, d1 = d1a + d1b;
#pragma unroll
    for (int off = 32; off; off >>= 1) {
        d0 += __shfl_xor(d0, off);
        d1 += __shfl_xor(d1, off);
    }
    if (l == 0) { red_u[p][h][0] = d0; red_u[p][h][1] = d1; }
    __syncthreads();

    const float u0 = red_u[p][0][0] + red_u[p][1][0];
    const float u1 = red_u[p][0][1] + red_u[p][1][1];
    const float rn0 = ro0 / fmaf(ro0, u0, EPS);
    const float rn1 = ro1 / fmaf(ro1, u1, EPS);
    if (h == 0 && l == 0) { r[i0] = rn0; r[i0 + 1] = rn1; }

    // acc = rn0*row0 + rn1*row1 over this half's 32 cols/lane
    float acc[32];
#pragma unroll
    for (int k = 0; k < 4; ++k) {
        acc[k*8+0] = fmaf(rn0, bf_lo(q0[k].x), rn1 * bf_lo(q1[k].x));
        acc[k*8+1] = fmaf(rn0, bf_hi(q0[k].x), rn1 * bf_hi(q1[k].x));
        acc[k*8+2] = fmaf(rn0, bf_lo(q0[k].y), rn1 * bf_lo(q1[k].y));
        acc[k*8+3] = fmaf(rn0, bf_hi(q0[k].y), rn1 * bf_hi(q1[k].y));
        acc[k*8+4] = fmaf(rn0, bf_lo(q0[k].z), rn1 * bf_lo(q1[k].z));
        acc[k*8+5] = fmaf(rn0, bf_hi(q0[k].z), rn1 * bf_hi(q1[k].z));
        acc[k*8+6] = fmaf(rn0, bf_lo(q0[k].w), rn1 * bf_lo(q1[k].w));
        acc[k*8+7] = fmaf(rn0, bf_hi(q0[k].w), rn1 * bf_hi(q1[k].w));
    }

    // cross-wave column reduce: buffer (h*4 + (p&3)), 512 float4 each.
    // lds4[buf][(2k+h2)*64 + l] holds within-half col-float4 (2l + 128k + h2)
    float4* lw = (float4*)lds + (h * 4 + (p & 3)) * 512;
    if (p < 4) {
#pragma unroll
        for (int k = 0; k < 4; ++k) {
#pragma unroll
            for (int h2 = 0; h2 < 2; ++h2) {
                lw[(2*k + h2) * 64 + l] = make_float4(acc[k*8+4*h2+0], acc[k*8+4*h2+1],
                                                      acc[k*8+4*h2+2], acc[k*8+4*h2+3]);
            }
        }
    }
    __syncthreads();
    if (p >= 4) {
#pragma unroll
        for (int k = 0; k < 4; ++k) {
#pragma unroll
            for (int h2 = 0; h2 < 2; ++h2) {
                const int idx = (2*k + h2) * 64 + l;
                float4 t = lw[idx];
                t.x += acc[k*8+4*h2+0];
                t.y += acc[k*8+4*h2+1];
                t.z += acc[k*8+4*h2+2];
                t.w += acc[k*8+4*h2+3];
                lw[idx] = t;
            }
        }
    }
    __syncthreads();

    // final: thread t outputs global col-float4 t. Within half: j4h = 128k+2l+h2.
    const float4* lr = (const float4*)lds;
    const int hh  = tid >> 9;
    const int j4h = tid & 511;
    const int k2  = j4h >> 7;
    const int rem = j4h & 127;
    const int idx = (2*k2 + (rem & 1)) * 64 + (rem >> 1);
    const int base = hh * 4 * 512;
    float4 s0 = lr[base + idx], s1 = lr[base + 512 + idx];
    float4 s2 = lr[base + 1024 + idx], s3 = lr[base + 1536 + idx];
    float4 s;
    s.x = (s0.x + s1.x) + (s2.x + s3.x);
    s.y = (s0.y + s1.y) + (s2.y + s3.y);
    s.z = (s0.z + s1.z) + (s2.z + s3.z);
    s.w = (s0.w + s1.w) + (s2.w + s3.w);
    ((float4*)(part + (size_t)b * N))[tid] = s;
}

// ---------------------------------------------------------------------------
// Kernel 3: v[j] = sum_b part[b][j];  c[j] = c[j]/(c[j]*v+eps)
// ---------------------------------------------------------------------------
__global__ void col_update(const float* __restrict__ part, float* __restrict__ c) {
    __shared__ float red[4][64];
    const int j0 = blockIdx.x * 64;
    const int jc = threadIdx.x & 63;
    const int g  = threadIdx.x >> 6;           // 0..3
    const int j  = j0 + jc;
    float v = 0.f;
#pragma unroll 8
    for (int k = 0; k < PASS_BLOCKS / 4; ++k)
        v += part[(size_t)(g * (PASS_BLOCKS / 4) + k) * N + j];
    red[g][jc] = v;
    __syncthreads();
    if (threadIdx.x < 64) {
        const float s = (red[0][jc] + red[1][jc]) + (red[2][jc] + red[3][jc]);
        const float cc = c[j];
        c[j] = cc / fmaf(cc, s, EPS);
    }
}

// ---------------------------------------------------------------------------
// Kernel 4: out[i][j] = r[i] * Sb[i][j] * c[j]   (Sb-sourced, no expf)
// ---------------------------------------------------------------------------
__global__ void finalize(const uint4* __restrict__ Sb, const float* __restrict__ r,
                         const float* __restrict__ c, float* __restrict__ out) {
    const int row = blockIdx.x;
    const int tid = threadIdx.x;
    const float rr = r[row];
    const uint4* Sr = Sb + (size_t)row * (N / 8);
    float4* o4 = (float4*)(out + (size_t)row * N);
    const float4* c4 = (const float4*)c;
#pragma unroll
    for (int t = 0; t < 2; ++t) {
        const int j8 = tid + 256 * t;          // uint4 index: cols 8*j8..8*j8+7
        uint4 qv = Sr[j8];
        float4 ca = c4[2*j8], cb = c4[2*j8 + 1];
        float4 o0, o1;
        o0.x = rr * bf_lo(qv.x) * ca.x;
        o0.y = rr * bf_hi(qv.x) * ca.y;
        o0.z = rr * bf_lo(qv.y) * ca.z;
        o0.w = rr * bf_hi(qv.y) * ca.w;
        o1.x = rr * bf_lo(qv.z) * cb.x;
        o1.y = rr * bf_hi(qv.z) * cb.y;
        o1.z = rr * bf_lo(qv.w) * cb.z;
        o1.w = rr * bf_hi(qv.w) * cb.w;
        o4[2*j8]     = o0;
        o4[2*j8 + 1] = o1;
    }
}

extern "C" void kernel_launch(void* const* d_in, const int* in_sizes, int n_in,
                              void* d_out, int out_size, void* d_ws, size_t ws_size,
                              hipStream_t stream) {
    const float* logits = (const float*)d_in[0];
    float* out = (float*)d_out;
    float* ws = (float*)d_ws;

    float* r    = ws;                          // [N]
    float* c    = ws + N;                      // [N]
    float* part = ws + 2 * N;                  // [PASS_BLOCKS][N] = 4 MB
    unsigned* Sb = (unsigned*)(part + (size_t)PASS_BLOCKS * N);  // bf16 [N][N] = 32 MB

    softmax_rows<<<N, 256, 0, stream>>>(logits, Sb, r, c);

    for (int it = 0; it < NIT; ++it) {
        sinkhorn_pass<<<PASS_BLOCKS, 1024, 0, stream>>>((const uint4*)Sb, r, c, part);
        col_update  <<<64,           256, 0, stream>>>(part, c);
    }

    finalize<<<N, 256, 0, stream>>>((const uint4*)Sb, r, c, out);
}